// Round 20
// baseline (230.127 us; speedup 1.0000x reference)
//
#include <hip/hip_runtime.h>
#include <hip/hip_bf16.h>
#include <math.h>

#define TSTEPS 128
#define HD 16      // GRU hidden
#define AD 32      // 2*H attention dim
#define CHUNK 8
#define NCHK 16
#define H1W 36     // K2 LDS row width in halfs
#define SEQ_HALFS 4096                   // per-seq history: 16c * 32u * 8
#define PH 264     // f16 stage pitch per seq (halfs): 8 rows*32 + 8 pad

#define SC1 1.44269504088896340736f   // log2(e)   : sigmoid prescale
#define SC2 2.88539008177792681472f   // 2*log2(e) : tanh prescale

typedef _Float16 h4 __attribute__((ext_vector_type(4)));
typedef _Float16 f16x8 __attribute__((ext_vector_type(8)));
typedef float f32x4 __attribute__((ext_vector_type(4)));

#if defined(__has_builtin)
#  if __has_builtin(__builtin_amdgcn_exp2f)
#    define EXP2F(x) __builtin_amdgcn_exp2f(x)
#  endif
#  if __has_builtin(__builtin_amdgcn_rcpf)
#    define RCPF(x) __builtin_amdgcn_rcpf(x)
#  endif
#endif
#ifndef EXP2F
#  define EXP2F(x) exp2f(x)
#endif
#ifndef RCPF
#  define RCPF(x) (1.0f / (x))
#endif

// tanh(x) with pre-scaled input u = 2*log2e*x
__device__ __forceinline__ float tanh_pre(float u) {
    return 1.0f - 2.0f * RCPF(EXP2F(u) + 1.0f);
}

// ---------------- K1: MFMA-datapath recurrence, coalesced-fed --------------
// Block = 128 threads = 2 waves; wave0 = fwd, wave1 = bwd over SIXTEEN seqs.
// Lane (sd = lane&15, ug = lane>>4); MFMA columns = the 16 seqs.
//   gx = Wih(+bias ch) . [x_t;1]  : 3x v_mfma_f32_16x16x32_f16
//   gh = Whh . h                  : 3x v_mfma_f32_16x16x16f16
// C layout of gh step s IS the B layout of step s+1 (verified R17-R19) -> the
// serial 8-step loop is PURE reg/MFMA/VALU: frags preloaded to registers at
// chunk start; x staged via coalesced dwordx4 -> raw-f32 LDS -> masked f16
// rows (bias ch. baked). All staging is off the serial chain.
template<int D>
__global__ __launch_bounds__(128, 1)
void gru_serial_kernel(
    const float* __restrict__ x,                      // [S, TSTEPS, D]
    const float* __restrict__ Wih_f, const float* __restrict__ Whh_f,
    const float* __restrict__ bih_f, const float* __restrict__ bhh_f,
    const float* __restrict__ Wih_b, const float* __restrict__ Whh_b,
    const float* __restrict__ bih_b, const float* __restrict__ bhh_b,
    _Float16* __restrict__ ghist)
{
    constexpr int RPS = 8 * D;                 // region floats per seq
    constexpr int NSP = RPS / 4;               // 16B spans per seq (50 / 32)
    constexpr int SPL = (NSP + 3) / 4;         // spans per lane (13 / 8)

    __shared__ __align__(16) float    xraw[2][16][RPS];        // 25.6/16.4 KB
    __shared__ __align__(16) _Float16 xf16[2][2][16 * PH];     // 33792 B

    const int tid  = threadIdx.x;
    const int lane = tid & 63;
    const int dir  = tid >> 6;           // wave0 = fwd, wave1 = bwd
    const int sd   = lane & 15;          // seq within block / MFMA column
    const int ug   = lane >> 4;          // unit/k group (0..3)

    const float* WihP = dir ? Wih_b : Wih_f;
    const float* WhhP = dir ? Whh_b : Whh_f;
    const float* bihP = dir ? bih_b : bih_f;
    const float* bhhP = dir ? bhh_b : bhh_f;

    // Whh A-frags (K=16): row = gate 16n+sd; k = 4*ug+e
    h4 whhA[3];
    #pragma unroll
    for (int n = 0; n < 3; ++n) {
        const float sc = (n < 2) ? SC1 : SC2;
        const int g = 16 * n + sd;
        #pragma unroll
        for (int e = 0; e < 4; ++e)
            whhA[n][e] = (_Float16)(WhhP[g * HD + 4 * ug + e] * sc);
    }
    // Wih A-frags (K=32, bias value at k==D): k = 8*ug+e
    f16x8 wihA[3];
    #pragma unroll
    for (int n = 0; n < 3; ++n) {
        const float sc = (n < 2) ? SC1 : SC2;
        const int g = 16 * n + sd;
        const float bias = (n < 2) ? (bihP[g] + bhhP[g]) : bihP[g];
        #pragma unroll
        for (int e = 0; e < 8; ++e) {
            const int k = 8 * ug + e;
            wihA[n][e] = (k < D) ? (_Float16)(WihP[g * D + k] * sc)
                       : (k == D) ? (_Float16)(bias * sc)
                       : (_Float16)0.0f;
        }
    }
    // n-gate hidden bias (multiplied by r): units 4*ug+e
    float bhn[4];
    #pragma unroll
    for (int e = 0; e < 4; ++e)
        bhn[e] = bhhP[2 * HD + 4 * ug + e] * SC2;

    // ---- staging roles ----
    const int sq  = lane >> 2;           // seq this lane stages (0..15)
    const int pst = lane & 3;            // quarter within seq
    const float* xseq = x + (size_t)(blockIdx.x * 16 + sq) * (TSTEPS * D);

    float4 g[SPL];                       // raw spans (static arrays, no lambdas)

    h4 bcur = (h4){(_Float16)0.0f, (_Float16)0.0f, (_Float16)0.0f, (_Float16)0.0f};
    float hw[4] = {0.0f, 0.0f, 0.0f, 0.0f};
    _Float16* ghbase = ghist + (size_t)(blockIdx.x * 16 + sd) * SEQ_HALFS
                       + (size_t)(dir * 16 + 4 * ug) * 8;
    const f32x4 z4 = {0.f, 0.f, 0.f, 0.f};

    // ---- prologue: stage chunk 0 into f16 buf 0 ----
    {
        const int tl = dir ? (TSTEPS - CHUNK) : 0;
        const float* rb = xseq + (size_t)tl * D;
        #pragma unroll
        for (int j = 0; j < SPL; ++j) {
            int sp = pst * SPL + j;
            if (sp > NSP - 1) sp = NSP - 1;               // duplicate-benign clamp
            g[j] = *reinterpret_cast<const float4*>(rb + 4 * sp);
        }
        #pragma unroll
        for (int j = 0; j < SPL; ++j) {
            int sp = pst * SPL + j;
            if (sp > NSP - 1) sp = NSP - 1;
            *reinterpret_cast<float4*>(&xraw[dir][sq][4 * sp]) = g[j];
        }
        // convert: this lane packs rows 2*pst, 2*pst+1 of seq sq
        #pragma unroll
        for (int rr2 = 0; rr2 < 2; ++rr2) {
            const int row = 2 * pst + rr2;
            const float* rp = &xraw[dir][sq][row * D];
            _Float16* wp = &xf16[dir][0][sq * PH + row * 32];
            #pragma unroll
            for (int part = 0; part < 4; ++part) {
                f16x8 w;
                #pragma unroll
                for (int e = 0; e < 8; ++e) {
                    const int k = part * 8 + e;
                    w[e] = (k < D) ? (_Float16)rp[k]
                         : (k == D) ? (_Float16)1.0f : (_Float16)0.0f;
                }
                *reinterpret_cast<f16x8*>(wp + part * 8) = w;
            }
        }
    }

    #pragma unroll 1
    for (int c = 0; c < NCHK; ++c) {
        // 1) issue next chunk's coalesced loads (covered by 8 serial steps)
        if (c + 1 < NCHK) {
            const int tl = dir ? (TSTEPS - CHUNK - CHUNK * (c + 1)) : (CHUNK * (c + 1));
            const float* rb = xseq + (size_t)tl * D;
            #pragma unroll
            for (int j = 0; j < SPL; ++j) {
                int sp = pst * SPL + j;
                if (sp > NSP - 1) sp = NSP - 1;
                g[j] = *reinterpret_cast<const float4*>(rb + 4 * sp);
            }
        }

        // 2) preload this chunk's 8 B-fragments into registers
        const _Float16* rdp = &xf16[dir][c & 1][sd * PH + ug * 8];
        f16x8 fr[8];
        #pragma unroll
        for (int ls = 0; ls < CHUNK; ++ls)
            fr[ls] = *reinterpret_cast<const f16x8*>(rdp + ls * 32);

        // 3) serial 8 steps: pure reg/MFMA/VALU
        f16x8 hrow[4];
        #pragma unroll
        for (int ls = 0; ls < CHUNK; ++ls) {
            const f16x8 frag = fr[ls];

            const f32x4 gxr = __builtin_amdgcn_mfma_f32_16x16x32_f16(wihA[0], frag, z4, 0, 0, 0);
            const f32x4 gxz = __builtin_amdgcn_mfma_f32_16x16x32_f16(wihA[1], frag, z4, 0, 0, 0);
            const f32x4 gxn = __builtin_amdgcn_mfma_f32_16x16x32_f16(wihA[2], frag, z4, 0, 0, 0);
            const f32x4 ghr = __builtin_amdgcn_mfma_f32_16x16x16f16(whhA[0], bcur, z4, 0, 0, 0);
            const f32x4 ghz = __builtin_amdgcn_mfma_f32_16x16x16f16(whhA[1], bcur, z4, 0, 0, 0);
            const f32x4 ghn = __builtin_amdgcn_mfma_f32_16x16x16f16(whhA[2], bcur, z4, 0, 0, 0);

            #pragma unroll
            for (int e = 0; e < 4; ++e) {
                const float rr = RCPF(1.0f + EXP2F(-(gxr[e] + ghr[e])));
                const float zz = RCPF(1.0f + EXP2F(-(gxz[e] + ghz[e])));
                const float nv = tanh_pre(gxn[e] + rr * (ghn[e] + bhn[e]));
                hw[e] = nv + zz * (hw[e] - nv);
                const _Float16 hh16 = (_Float16)hw[e];
                bcur[e] = hh16;
                hrow[e][ls] = hh16;
            }
        }

        // 4) history store: 4x 16B contiguous per lane; bwd chunk-reversed
        const int cc = dir ? (NCHK - 1 - c) : c;
        _Float16* gp = ghbase + (size_t)cc * 256;
        #pragma unroll
        for (int e = 0; e < 4; ++e)
            *reinterpret_cast<f16x8*>(gp + e * 8) = hrow[e];

        // 5) raw write + convert next chunk into f16 buf ((c+1)&1)
        if (c + 1 < NCHK) {
            #pragma unroll
            for (int j = 0; j < SPL; ++j) {
                int sp = pst * SPL + j;
                if (sp > NSP - 1) sp = NSP - 1;
                *reinterpret_cast<float4*>(&xraw[dir][sq][4 * sp]) = g[j];
            }
            #pragma unroll
            for (int rr2 = 0; rr2 < 2; ++rr2) {
                const int row = 2 * pst + rr2;
                const float* rp = &xraw[dir][sq][row * D];
                _Float16* wp = &xf16[dir][(c + 1) & 1][sq * PH + row * 32];
                #pragma unroll
                for (int part = 0; part < 4; ++part) {
                    f16x8 w;
                    #pragma unroll
                    for (int e = 0; e < 8; ++e) {
                        const int k = part * 8 + e;
                        w[e] = (k < D) ? (_Float16)rp[k]
                             : (k == D) ? (_Float16)1.0f : (_Float16)0.0f;
                    }
                    *reinterpret_cast<f16x8*>(wp + part * 8) = w;
                }
            }
        }
    }
}

// ---------------- K2: attention over the streamed history (unchanged) ------
template<bool HAS_PROJ>
__global__ __launch_bounds__(128, 4)
void attn_kernel(
    const _Float16* __restrict__ ghist,
    const float* __restrict__ Wa, const float* __restrict__ ba,
    const float* __restrict__ ctxv,
    const float* __restrict__ Wm, const float* __restrict__ bm,
    float* __restrict__ out, int out_cols)
{
    __shared__ __align__(16) _Float16 h1[TSTEPS * H1W];   // 9216 B
    __shared__ float w_sh[TSTEPS];
    __shared__ float red[4];
    __shared__ float cvp[4 * AD];

    const int tid  = threadIdx.x;
    const int lane = tid & 63;
    const int wave = tid >> 6;
    const int seq  = blockIdx.x;

    // stage ghist[seq] -> h1[t][u32]  (coalesced f16x8 loads)
    {
        const f16x8* src = reinterpret_cast<const f16x8*>(ghist + (size_t)seq * SEQ_HALFS);
        #pragma unroll
        for (int k = 0; k < 4; ++k) {
            const int idx = tid + k * 128;
            const f16x8 v = src[idx];
            const int u32 = idx & 31;
            const int tb  = (idx >> 5) * 8;
            const int flip = (u32 >= 16) ? 7 : 0;   // bwd chunks are s-ordered
            #pragma unroll
            for (int e = 0; e < 8; ++e)
                h1[(tb + (e ^ flip)) * H1W + u32] = v[e];
        }
    }
    __syncthreads();

    // tanh proj -> softmax over t
    {
        const int t = tid;
        float hh[AD];
        const h4* hr = reinterpret_cast<const h4*>(&h1[t * H1W]);
        #pragma unroll
        for (int pp = 0; pp < AD / 4; ++pp) {
            const h4 v = hr[pp];
            #pragma unroll
            for (int e = 0; e < 4; ++e) hh[4 * pp + e] = (float)v[e];
        }
        float st = 0.0f;
        for (int i = 0; i < AD; ++i) {
            float a0 = ba[i], a1 = 0.f;
            const float* war = &Wa[i * AD];
            #pragma unroll
            for (int k = 0; k < AD; k += 2) {
                a0 += war[k] * hh[k];
                a1 += war[k + 1] * hh[k + 1];
            }
            st += tanh_pre(SC2 * (a0 + a1)) * ctxv[i];
        }
        float m = st;
        #pragma unroll
        for (int off = 32; off > 0; off >>= 1) m = fmaxf(m, __shfl_xor(m, off));
        if (lane == 0) red[wave] = m;
        __syncthreads();
        m = fmaxf(red[0], red[1]);
        const float e = EXP2F(SC1 * (st - m));
        float ssum = e;
        #pragma unroll
        for (int off = 32; off > 0; off >>= 1) ssum += __shfl_xor(ssum, off);
        if (lane == 0) red[2 + wave] = ssum;
        __syncthreads();
        const float Z = red[2] + red[3];
        w_sh[tid] = e * RCPF(Z);
    }
    __syncthreads();

    // cv[i] = sum_t w[t] * h1[t][i]
    {
        const int g = tid >> 5, i = tid & 31;
        float acc = 0.0f;
        for (int k = 0; k < 32; ++k) {
            const int tt = g * 32 + k;
            acc += w_sh[tt] * (float)h1[tt * H1W + i];
        }
        cvp[g * AD + i] = acc;
    }
    __syncthreads();
    if (tid < AD)
        cvp[tid] = cvp[tid] + cvp[AD + tid] + cvp[2 * AD + tid] + cvp[3 * AD + tid];
    __syncthreads();

    if (HAS_PROJ) {
        if (tid < HD) {
            float acc = bm[tid];
            #pragma unroll
            for (int i = 0; i < AD; ++i) acc += Wm[tid * AD + i] * cvp[i];
            out[(size_t)seq * out_cols + tid] = acc;
        }
    } else {
        if (tid < AD) out[(size_t)seq * out_cols + tid] = cvp[tid];
    }
}

extern "C" void kernel_launch(void* const* d_in, const int* in_sizes, int n_in,
                              void* d_out, int out_size, void* d_ws, size_t ws_size,
                              hipStream_t stream) {
    const float* x     = (const float*)d_in[0];
    const float* Wih1f = (const float*)d_in[1];
    const float* Whh1f = (const float*)d_in[2];
    const float* bih1f = (const float*)d_in[3];
    const float* bhh1f = (const float*)d_in[4];
    const float* Wih1b = (const float*)d_in[5];
    const float* Whh1b = (const float*)d_in[6];
    const float* bih1b = (const float*)d_in[7];
    const float* bhh1b = (const float*)d_in[8];
    const float* Wih2f = (const float*)d_in[9];
    const float* Whh2f = (const float*)d_in[10];
    const float* bih2f = (const float*)d_in[11];
    const float* bhh2f = (const float*)d_in[12];
    const float* Wih2b = (const float*)d_in[13];
    const float* Whh2b = (const float*)d_in[14];
    const float* bih2b = (const float*)d_in[15];
    const float* bhh2b = (const float*)d_in[16];
    const float* Wa1   = (const float*)d_in[17];
    const float* ba1   = (const float*)d_in[18];
    const float* ctx1  = (const float*)d_in[19];
    const float* Wa2   = (const float*)d_in[20];
    const float* ba2   = (const float*)d_in[21];
    const float* ctx2  = (const float*)d_in[22];
    const float* Wm    = (const float*)d_in[23];
    const float* bm    = (const float*)d_in[24];

    float* flow = (float*)d_ws;                               // [8192,16] = 512KB
    const size_t histOff = 1u << 20;                          // 1 MB
    _Float16* ghist = (_Float16*)((char*)d_ws + histOff);     // 64 MB (reused by s2)
    float* outp = (float*)d_out;                              // [64, 32]

    // Stage 1: 8192 seqs, 16 per block -> history; then attention -> flow
    gru_serial_kernel<25><<<512, 128, 0, stream>>>(
        x, Wih1f, Whh1f, bih1f, bhh1f, Wih1b, Whh1b, bih1b, bhh1b, ghist);
    attn_kernel<true><<<8192, 128, 0, stream>>>(
        ghist, Wa1, ba1, ctx1, Wm, bm, flow, 16);

    // Stage 2: 64 seqs (input = flow as [64,128,16]); ghist buffer reused
    gru_serial_kernel<16><<<4, 128, 0, stream>>>(
        flow, Wih2f, Whh2f, bih2f, bhh2f, Wih2b, Whh2b, bih2b, bhh2b, ghist);
    attn_kernel<false><<<64, 128, 0, stream>>>(
        ghist, Wa2, ba2, ctx2, nullptr, nullptr, outp, 32);
}

// Round 21
// 184.732 us; speedup vs baseline: 1.2457x; 1.2457x over previous
//
#include <hip/hip_runtime.h>
#include <hip/hip_bf16.h>
#include <math.h>

#define TSTEPS 128
#define HD 16      // GRU hidden
#define AD 32      // 2*H attention dim
#define CHUNK 8
#define NCHK 16
#define H1W 36     // K2 LDS row width in halfs
#define SEQ_HALFS 4096                   // per-seq history: 16c * 32u * 8
#define PH 264     // f16 stage pitch per seq (halfs)

#define SC1 1.44269504088896340736f   // log2(e)   : sigmoid prescale
#define SC2 2.88539008177792681472f   // 2*log2(e) : tanh prescale

typedef _Float16 h4 __attribute__((ext_vector_type(4)));
typedef _Float16 f16x8 __attribute__((ext_vector_type(8)));
typedef float f32x4 __attribute__((ext_vector_type(4)));

#if defined(__has_builtin)
#  if __has_builtin(__builtin_amdgcn_exp2f)
#    define EXP2F(x) __builtin_amdgcn_exp2f(x)
#  endif
#  if __has_builtin(__builtin_amdgcn_rcpf)
#    define RCPF(x) __builtin_amdgcn_rcpf(x)
#  endif
#  if __has_builtin(__builtin_amdgcn_global_load_lds)
#    define HAS_GLDS 1
#  endif
#endif
#ifndef EXP2F
#  define EXP2F(x) exp2f(x)
#endif
#ifndef RCPF
#  define RCPF(x) (1.0f / (x))
#endif

// tanh(x) with pre-scaled input u = 2*log2e*x
__device__ __forceinline__ float tanh_pre(float u) {
    return 1.0f - 2.0f * RCPF(EXP2F(u) + 1.0f);
}

#ifdef HAS_GLDS
typedef const __attribute__((address_space(1))) void gas_t;
typedef __attribute__((address_space(3))) void las_t;
#endif

// ---------------- K1: MFMA-datapath recurrence, global_load_lds-fed --------
// Block = 128 threads = 2 waves; wave0 = fwd, wave1 = bwd over SIXTEEN seqs.
// Lane (sd = lane&15, ug = lane>>4); MFMA columns = the 16 seqs.
//   gx = Wih(+bias ch) . [x_t;1]  : 3x v_mfma_f32_16x16x32_f16
//   gh = Whh . h                  : 3x v_mfma_f32_16x16x16f16
// C layout of gh step s IS the B layout of step s+1 (verified R17-R20).
// x region staged per-chunk via 13x global_load_lds width=16 (lane-linear
// span layout, no VGPR round-trip, no in-chunk-top stall); vmcnt(0) only
// before the end-of-chunk f16 conversion (covered by the 8 serial steps).
// NOTHING bulky lives across the serial loop (R20 spill lesson).
template<int D>
__global__ __launch_bounds__(128, 1)
void gru_serial_kernel(
    const float* __restrict__ x,                      // [S, TSTEPS, D]
    const float* __restrict__ Wih_f, const float* __restrict__ Whh_f,
    const float* __restrict__ bih_f, const float* __restrict__ bhh_f,
    const float* __restrict__ Wih_b, const float* __restrict__ Whh_b,
    const float* __restrict__ bih_b, const float* __restrict__ bhh_b,
    _Float16* __restrict__ ghist)
{
    constexpr int NSPAN = (8 * D) / 4;            // 16B spans per seq region
    constexpr int TSPAN = 16 * NSPAN;             // spans per wave region
    constexpr int SPL   = (TSPAN + 63) / 64;      // staging instrs per chunk

    __shared__ __align__(16) float    xraw[2][SPL * 64 * 4];
    __shared__ __align__(16) _Float16 xf16[2][2][16 * PH];

    const int tid  = threadIdx.x;
    const int lane = tid & 63;
    const int dir  = tid >> 6;           // wave0 = fwd, wave1 = bwd
    const int dirw = __builtin_amdgcn_readfirstlane(dir);
    const int sd   = lane & 15;          // seq within block / MFMA column
    const int ug   = lane >> 4;          // unit/k group (0..3)

    const float* WihP = dir ? Wih_b : Wih_f;
    const float* WhhP = dir ? Whh_b : Whh_f;
    const float* bihP = dir ? bih_b : bih_f;
    const float* bhhP = dir ? bhh_b : bhh_f;

    // Whh A-frags (K=16): row = gate 16n+sd; k = 4*ug+e
    h4 whhA[3];
    #pragma unroll
    for (int n = 0; n < 3; ++n) {
        const float sc = (n < 2) ? SC1 : SC2;
        const int g = 16 * n + sd;
        #pragma unroll
        for (int e = 0; e < 4; ++e)
            whhA[n][e] = (_Float16)(WhhP[g * HD + 4 * ug + e] * sc);
    }
    // Wih A-frags (K=32, bias value at k==D): k = 8*ug+e
    f16x8 wihA[3];
    #pragma unroll
    for (int n = 0; n < 3; ++n) {
        const float sc = (n < 2) ? SC1 : SC2;
        const int g = 16 * n + sd;
        const float bias = (n < 2) ? (bihP[g] + bhhP[g]) : bihP[g];
        #pragma unroll
        for (int e = 0; e < 8; ++e) {
            const int k = 8 * ug + e;
            wihA[n][e] = (k < D) ? (_Float16)(WihP[g * D + k] * sc)
                       : (k == D) ? (_Float16)(bias * sc)
                       : (_Float16)0.0f;
        }
    }
    // n-gate hidden bias (multiplied by r): units 4*ug+e
    float bhn[4];
    #pragma unroll
    for (int e = 0; e < 4; ++e)
        bhn[e] = bhhP[2 * HD + 4 * ug + e] * SC2;

    // per-j global byte offsets for staging (span s = j*64+lane, clamped)
    unsigned goff[SPL];
    #pragma unroll
    for (int j = 0; j < SPL; ++j) {
        int s = j * 64 + lane;
        if (s > TSPAN - 1) s = TSPAN - 1;            // dup-benign clamp
        const int sq2 = s / NSPAN;
        const int sp  = s - sq2 * NSPAN;
        goff[j] = (unsigned)(((blockIdx.x * 16 + sq2) * (TSTEPS * D) + sp * 4) * 4);
    }
    const char* xbytes = (const char*)x;

    // conversion roles: lane (sq = lane>>2) packs rows 2*pst, 2*pst+1
    const int sq  = lane >> 2;
    const int pst = lane & 3;

    h4 bcur = (h4){(_Float16)0.0f, (_Float16)0.0f, (_Float16)0.0f, (_Float16)0.0f};
    float hw[4] = {0.0f, 0.0f, 0.0f, 0.0f};
    _Float16* ghbase = ghist + (size_t)(blockIdx.x * 16 + sd) * SEQ_HALFS
                       + (size_t)(dir * 16 + 4 * ug) * 8;
    const f32x4 z4 = {0.f, 0.f, 0.f, 0.f};

    // ---- staging macro-equivalents (written inline, no lambdas) ----
    // stage chunk cc raw region (fire-and-forget)
    // toffB = t_low(cc) * D * 4 bytes; t_low multiple of 8 -> 16B aligned
    #define STAGE_RAW(cc)                                                     \
    {                                                                         \
        const unsigned toffB = (unsigned)((dir ? (TSTEPS - CHUNK - CHUNK*(cc)) \
                                               : (CHUNK*(cc))) * D * 4);      \
        _Pragma("unroll")                                                     \
        for (int j = 0; j < SPL; ++j) {                                       \
            const char* gp = xbytes + goff[j] + toffB;                        \
            char* lp = (char*)&xraw[dirw][0] + j * 1024;                      \
            STAGE_ONE(gp, lp);                                                \
        }                                                                     \
    }
    #ifdef HAS_GLDS
    #define STAGE_ONE(gp, lp) \
        __builtin_amdgcn_global_load_lds((gas_t*)(gp), (las_t*)(lp), 16, 0, 0);
    #else
    #define STAGE_ONE(gp, lp) \
        { const float4 v_ = *reinterpret_cast<const float4*>(gp); \
          *reinterpret_cast<float4*>((lp) + lane * 16) = v_; }
    #endif

    // convert raw -> xf16 buf b (pre-masked rows, bias ch. at k==D)
    #define CONVERT(b)                                                        \
    {                                                                         \
        _Pragma("unroll")                                                     \
        for (int rr2 = 0; rr2 < 2; ++rr2) {                                   \
            const int row = 2 * pst + rr2;                                    \
            const float* rp = &xraw[dirw][0] + sq * (8 * D) + row * D;        \
            _Float16* wp = &xf16[dirw][b][sq * PH + row * 32];                \
            _Pragma("unroll")                                                 \
            for (int part = 0; part < 4; ++part) {                            \
                f16x8 w;                                                      \
                _Pragma("unroll")                                             \
                for (int e = 0; e < 8; ++e) {                                 \
                    const int k = part * 8 + e;                               \
                    w[e] = (k < D) ? (_Float16)rp[k]                          \
                         : (k == D) ? (_Float16)1.0f : (_Float16)0.0f;        \
                }                                                             \
                *reinterpret_cast<f16x8*>(wp + part * 8) = w;                 \
            }                                                                 \
        }                                                                     \
    }

    // ---- prologue: stage + convert chunk 0 ----
    STAGE_RAW(0);
    asm volatile("s_waitcnt vmcnt(0)" ::: "memory");
    CONVERT(0);

    #pragma unroll 1
    for (int c = 0; c < NCHK; ++c) {
        // 1) fire next chunk's staging (no wait; covered by serial loop)
        if (c + 1 < NCHK) STAGE_RAW(c + 1);

        const _Float16* rdp = &xf16[dirw][c & 1][sd * PH + ug * 8];

        // 2) serial 8 steps, rolling 1-ahead frag prefetch (2 frags live)
        f16x8 hrow[4];
        f16x8 fA = *reinterpret_cast<const f16x8*>(rdp);
        #pragma unroll
        for (int ls = 0; ls < CHUNK; ++ls) {
            f16x8 fB;
            if (ls + 1 < CHUNK)
                fB = *reinterpret_cast<const f16x8*>(rdp + (ls + 1) * 32);

            const f32x4 gxr = __builtin_amdgcn_mfma_f32_16x16x32_f16(wihA[0], fA, z4, 0, 0, 0);
            const f32x4 gxz = __builtin_amdgcn_mfma_f32_16x16x32_f16(wihA[1], fA, z4, 0, 0, 0);
            const f32x4 gxn = __builtin_amdgcn_mfma_f32_16x16x32_f16(wihA[2], fA, z4, 0, 0, 0);
            const f32x4 ghr = __builtin_amdgcn_mfma_f32_16x16x16f16(whhA[0], bcur, z4, 0, 0, 0);
            const f32x4 ghz = __builtin_amdgcn_mfma_f32_16x16x16f16(whhA[1], bcur, z4, 0, 0, 0);
            const f32x4 ghn = __builtin_amdgcn_mfma_f32_16x16x16f16(whhA[2], bcur, z4, 0, 0, 0);

            #pragma unroll
            for (int e = 0; e < 4; ++e) {
                const float rr = RCPF(1.0f + EXP2F(-(gxr[e] + ghr[e])));
                const float zz = RCPF(1.0f + EXP2F(-(gxz[e] + ghz[e])));
                const float nv = tanh_pre(gxn[e] + rr * (ghn[e] + bhn[e]));
                hw[e] = nv + zz * (hw[e] - nv);
                const _Float16 hh16 = (_Float16)hw[e];
                bcur[e] = hh16;
                hrow[e][ls] = hh16;
            }
            if (ls + 1 < CHUNK) fA = fB;
        }

        // 3) history store: 4x 16B contiguous per lane; bwd chunk-reversed
        const int cc2 = dir ? (NCHK - 1 - c) : c;
        _Float16* gp2 = ghbase + (size_t)cc2 * 256;
        #pragma unroll
        for (int e = 0; e < 4; ++e)
            *reinterpret_cast<f16x8*>(gp2 + e * 8) = hrow[e];

        // 4) drain staging loads, convert next chunk into other f16 buf
        if (c + 1 < NCHK) {
            asm volatile("s_waitcnt vmcnt(0)" ::: "memory");
            CONVERT((c + 1) & 1);
        }
    }
    #undef STAGE_RAW
    #undef STAGE_ONE
    #undef CONVERT
}

// ---------------- K2: attention over the streamed history (unchanged) ------
template<bool HAS_PROJ>
__global__ __launch_bounds__(128, 4)
void attn_kernel(
    const _Float16* __restrict__ ghist,
    const float* __restrict__ Wa, const float* __restrict__ ba,
    const float* __restrict__ ctxv,
    const float* __restrict__ Wm, const float* __restrict__ bm,
    float* __restrict__ out, int out_cols)
{
    __shared__ __align__(16) _Float16 h1[TSTEPS * H1W];   // 9216 B
    __shared__ float w_sh[TSTEPS];
    __shared__ float red[4];
    __shared__ float cvp[4 * AD];

    const int tid  = threadIdx.x;
    const int lane = tid & 63;
    const int wave = tid >> 6;
    const int seq  = blockIdx.x;

    // stage ghist[seq] -> h1[t][u32]  (coalesced f16x8 loads)
    {
        const f16x8* src = reinterpret_cast<const f16x8*>(ghist + (size_t)seq * SEQ_HALFS);
        #pragma unroll
        for (int k = 0; k < 4; ++k) {
            const int idx = tid + k * 128;
            const f16x8 v = src[idx];
            const int u32 = idx & 31;
            const int tb  = (idx >> 5) * 8;
            const int flip = (u32 >= 16) ? 7 : 0;   // bwd chunks are s-ordered
            #pragma unroll
            for (int e = 0; e < 8; ++e)
                h1[(tb + (e ^ flip)) * H1W + u32] = v[e];
        }
    }
    __syncthreads();

    // tanh proj -> softmax over t
    {
        const int t = tid;
        float hh[AD];
        const h4* hr = reinterpret_cast<const h4*>(&h1[t * H1W]);
        #pragma unroll
        for (int pp = 0; pp < AD / 4; ++pp) {
            const h4 v = hr[pp];
            #pragma unroll
            for (int e = 0; e < 4; ++e) hh[4 * pp + e] = (float)v[e];
        }
        float st = 0.0f;
        for (int i = 0; i < AD; ++i) {
            float a0 = ba[i], a1 = 0.f;
            const float* war = &Wa[i * AD];
            #pragma unroll
            for (int k = 0; k < AD; k += 2) {
                a0 += war[k] * hh[k];
                a1 += war[k + 1] * hh[k + 1];
            }
            st += tanh_pre(SC2 * (a0 + a1)) * ctxv[i];
        }
        float m = st;
        #pragma unroll
        for (int off = 32; off > 0; off >>= 1) m = fmaxf(m, __shfl_xor(m, off));
        if (lane == 0) red[wave] = m;
        __syncthreads();
        m = fmaxf(red[0], red[1]);
        const float e = EXP2F(SC1 * (st - m));
        float ssum = e;
        #pragma unroll
        for (int off = 32; off > 0; off >>= 1) ssum += __shfl_xor(ssum, off);
        if (lane == 0) red[2 + wave] = ssum;
        __syncthreads();
        const float Z = red[2] + red[3];
        w_sh[tid] = e * RCPF(Z);
    }
    __syncthreads();

    // cv[i] = sum_t w[t] * h1[t][i]
    {
        const int g = tid >> 5, i = tid & 31;
        float acc = 0.0f;
        for (int k = 0; k < 32; ++k) {
            const int tt = g * 32 + k;
            acc += w_sh[tt] * (float)h1[tt * H1W + i];
        }
        cvp[g * AD + i] = acc;
    }
    __syncthreads();
    if (tid < AD)
        cvp[tid] = cvp[tid] + cvp[AD + tid] + cvp[2 * AD + tid] + cvp[3 * AD + tid];
    __syncthreads();

    if (HAS_PROJ) {
        if (tid < HD) {
            float acc = bm[tid];
            #pragma unroll
            for (int i = 0; i < AD; ++i) acc += Wm[tid * AD + i] * cvp[i];
            out[(size_t)seq * out_cols + tid] = acc;
        }
    } else {
        if (tid < AD) out[(size_t)seq * out_cols + tid] = cvp[tid];
    }
}

extern "C" void kernel_launch(void* const* d_in, const int* in_sizes, int n_in,
                              void* d_out, int out_size, void* d_ws, size_t ws_size,
                              hipStream_t stream) {
    const float* x     = (const float*)d_in[0];
    const float* Wih1f = (const float*)d_in[1];
    const float* Whh1f = (const float*)d_in[2];
    const float* bih1f = (const float*)d_in[3];
    const float* bhh1f = (const float*)d_in[4];
    const float* Wih1b = (const float*)d_in[5];
    const float* Whh1b = (const float*)d_in[6];
    const float* bih1b = (const float*)d_in[7];
    const float* bhh1b = (const float*)d_in[8];
    const float* Wih2f = (const float*)d_in[9];
    const float* Whh2f = (const float*)d_in[10];
    const float* bih2f = (const float*)d_in[11];
    const float* bhh2f = (const float*)d_in[12];
    const float* Wih2b = (const float*)d_in[13];
    const float* Whh2b = (const float*)d_in[14];
    const float* bih2b = (const float*)d_in[15];
    const float* bhh2b = (const float*)d_in[16];
    const float* Wa1   = (const float*)d_in[17];
    const float* ba1   = (const float*)d_in[18];
    const float* ctx1  = (const float*)d_in[19];
    const float* Wa2   = (const float*)d_in[20];
    const float* ba2   = (const float*)d_in[21];
    const float* ctx2  = (const float*)d_in[22];
    const float* Wm    = (const float*)d_in[23];
    const float* bm    = (const float*)d_in[24];

    float* flow = (float*)d_ws;                               // [8192,16] = 512KB
    const size_t histOff = 1u << 20;                          // 1 MB
    _Float16* ghist = (_Float16*)((char*)d_ws + histOff);     // 64 MB (reused by s2)
    float* outp = (float*)d_out;                              // [64, 32]

    // Stage 1: 8192 seqs, 16 per block -> history; then attention -> flow
    gru_serial_kernel<25><<<512, 128, 0, stream>>>(
        x, Wih1f, Whh1f, bih1f, bhh1f, Wih1b, Whh1b, bih1b, bhh1b, ghist);
    attn_kernel<true><<<8192, 128, 0, stream>>>(
        ghist, Wa1, ba1, ctx1, Wm, bm, flow, 16);

    // Stage 2: 64 seqs (input = flow as [64,128,16]); ghist buffer reused
    gru_serial_kernel<16><<<4, 128, 0, stream>>>(
        flow, Wih2f, Whh2f, bih2f, bhh2f, Wih2b, Whh2b, bih2b, bhh2b, ghist);
    attn_kernel<false><<<64, 128, 0, stream>>>(
        ghist, Wa2, ba2, ctx2, nullptr, nullptr, outp, 32);
}

// Round 22
// 154.008 us; speedup vs baseline: 1.4942x; 1.1995x over previous
//
#include <hip/hip_runtime.h>
#include <hip/hip_bf16.h>
#include <math.h>

#define TSTEPS 128
#define HD 16      // GRU hidden
#define AD 32      // 2*H attention dim
#define CHUNK 8
#define NCHK 16
#define H1W 36     // K2 LDS row width in halfs
#define SEQ_HALFS 4096                   // per-seq history: 16c * 32u * 8
#define PH 264     // f16 stage pitch per seq (halfs)

#define SC1 1.44269504088896340736f   // log2(e)   : sigmoid prescale
#define SC2 2.88539008177792681472f   // 2*log2(e) : tanh prescale

typedef _Float16 h4 __attribute__((ext_vector_type(4)));
typedef _Float16 f16x8 __attribute__((ext_vector_type(8)));
typedef float f32x4 __attribute__((ext_vector_type(4)));

#if defined(__has_builtin)
#  if __has_builtin(__builtin_amdgcn_exp2f)
#    define EXP2F(x) __builtin_amdgcn_exp2f(x)
#  endif
#  if __has_builtin(__builtin_amdgcn_rcpf)
#    define RCPF(x) __builtin_amdgcn_rcpf(x)
#  endif
#  if __has_builtin(__builtin_amdgcn_global_load_lds)
#    define HAS_GLDS 1
#  endif
#endif
#ifndef EXP2F
#  define EXP2F(x) exp2f(x)
#endif
#ifndef RCPF
#  define RCPF(x) (1.0f / (x))
#endif

// tanh(x) with pre-scaled input u = 2*log2e*x
__device__ __forceinline__ float tanh_pre(float u) {
    return 1.0f - 2.0f * RCPF(EXP2F(u) + 1.0f);
}

#ifdef HAS_GLDS
typedef const __attribute__((address_space(1))) void gas_t;
typedef __attribute__((address_space(3))) void las_t;
#endif

// pack one padded f16 row: [0..D) = data, [D] = 1.0 (bias ch.), rest = 0
template<int D>
__device__ __forceinline__ void store_row(_Float16* wp, const float* v) {
    #pragma unroll
    for (int part = 0; part < 4; ++part) {
        f16x8 w;
        #pragma unroll
        for (int e = 0; e < 8; ++e) {
            const int k = part * 8 + e;
            w[e] = (k < D) ? (_Float16)v[k]
                 : (k == D) ? (_Float16)1.0f : (_Float16)0.0f;
        }
        *reinterpret_cast<f16x8*>(wp + part * 8) = w;
    }
}

// ---------------- K1a: MFMA-datapath recurrence, global_load_lds-fed -------
// (stage 1: x streamed from HBM). Counted vmcnt(4): the 4 history stores stay
// in flight across the chunk boundary; only staging loads drain before CONVERT.
template<int D>
__global__ __launch_bounds__(128, 1)
void gru_serial_glds(
    const float* __restrict__ x,                      // [S, TSTEPS, D]
    const float* __restrict__ Wih_f, const float* __restrict__ Whh_f,
    const float* __restrict__ bih_f, const float* __restrict__ bhh_f,
    const float* __restrict__ Wih_b, const float* __restrict__ Whh_b,
    const float* __restrict__ bih_b, const float* __restrict__ bhh_b,
    _Float16* __restrict__ ghist)
{
    constexpr int NSPAN = (8 * D) / 4;            // 16B spans per seq region
    constexpr int TSPAN = 16 * NSPAN;             // spans per wave region
    constexpr int SPL   = (TSPAN + 63) / 64;      // staging instrs per chunk

    __shared__ __align__(16) float    xraw[2][SPL * 64 * 4];
    __shared__ __align__(16) _Float16 xf16[2][2][16 * PH];

    const int tid  = threadIdx.x;
    const int lane = tid & 63;
    const int dir  = tid >> 6;           // wave0 = fwd, wave1 = bwd
    const int dirw = __builtin_amdgcn_readfirstlane(dir);
    const int sd   = lane & 15;          // seq within block / MFMA column
    const int ug   = lane >> 4;          // unit/k group (0..3)

    const float* WihP = dir ? Wih_b : Wih_f;
    const float* WhhP = dir ? Whh_b : Whh_f;
    const float* bihP = dir ? bih_b : bih_f;
    const float* bhhP = dir ? bhh_b : bhh_f;

    // Whh A-frags (K=16): row = gate 16n+sd; k = 4*ug+e
    h4 whhA[3];
    #pragma unroll
    for (int n = 0; n < 3; ++n) {
        const float sc = (n < 2) ? SC1 : SC2;
        const int g = 16 * n + sd;
        #pragma unroll
        for (int e = 0; e < 4; ++e)
            whhA[n][e] = (_Float16)(WhhP[g * HD + 4 * ug + e] * sc);
    }
    // Wih A-frags (K=32, bias value at k==D): k = 8*ug+e
    f16x8 wihA[3];
    #pragma unroll
    for (int n = 0; n < 3; ++n) {
        const float sc = (n < 2) ? SC1 : SC2;
        const int g = 16 * n + sd;
        const float bias = (n < 2) ? (bihP[g] + bhhP[g]) : bihP[g];
        #pragma unroll
        for (int e = 0; e < 8; ++e) {
            const int k = 8 * ug + e;
            wihA[n][e] = (k < D) ? (_Float16)(WihP[g * D + k] * sc)
                       : (k == D) ? (_Float16)(bias * sc)
                       : (_Float16)0.0f;
        }
    }
    // n-gate hidden bias (multiplied by r): units 4*ug+e
    float bhn[4];
    #pragma unroll
    for (int e = 0; e < 4; ++e)
        bhn[e] = bhhP[2 * HD + 4 * ug + e] * SC2;

    // per-j global byte offsets for staging (span s = j*64+lane, clamped)
    unsigned goff[SPL];
    #pragma unroll
    for (int j = 0; j < SPL; ++j) {
        int s = j * 64 + lane;
        if (s > TSPAN - 1) s = TSPAN - 1;            // dup-benign clamp
        const int sq2 = s / NSPAN;
        const int sp  = s - sq2 * NSPAN;
        goff[j] = (unsigned)(((blockIdx.x * 16 + sq2) * (TSTEPS * D) + sp * 4) * 4);
    }
    const char* xbytes = (const char*)x;

    // conversion roles: lane (sq = lane>>2) packs rows 2*pst, 2*pst+1
    const int sq  = lane >> 2;
    const int pst = lane & 3;

    h4 bcur = (h4){(_Float16)0.0f, (_Float16)0.0f, (_Float16)0.0f, (_Float16)0.0f};
    float hw[4] = {0.0f, 0.0f, 0.0f, 0.0f};
    _Float16* ghbase = ghist + (size_t)(blockIdx.x * 16 + sd) * SEQ_HALFS
                       + (size_t)(dir * 16 + 4 * ug) * 8;
    const f32x4 z4 = {0.f, 0.f, 0.f, 0.f};

    #define STAGE_RAW(cc)                                                     \
    {                                                                         \
        const unsigned toffB = (unsigned)((dir ? (TSTEPS - CHUNK - CHUNK*(cc)) \
                                               : (CHUNK*(cc))) * D * 4);      \
        _Pragma("unroll")                                                     \
        for (int j = 0; j < SPL; ++j) {                                       \
            const char* gp = xbytes + goff[j] + toffB;                        \
            char* lp = (char*)&xraw[dirw][0] + j * 1024;                      \
            STAGE_ONE(gp, lp);                                                \
        }                                                                     \
    }
    #ifdef HAS_GLDS
    #define STAGE_ONE(gp, lp) \
        __builtin_amdgcn_global_load_lds((gas_t*)(gp), (las_t*)(lp), 16, 0, 0);
    #else
    #define STAGE_ONE(gp, lp) \
        { const float4 v_ = *reinterpret_cast<const float4*>(gp); \
          *reinterpret_cast<float4*>((lp) + lane * 16) = v_; }
    #endif

    #define CONVERT(b)                                                        \
    {                                                                         \
        _Pragma("unroll")                                                     \
        for (int rr2 = 0; rr2 < 2; ++rr2) {                                   \
            const int row = 2 * pst + rr2;                                    \
            const float* rp = &xraw[dirw][0] + sq * (8 * D) + row * D;        \
            _Float16* wp = &xf16[dirw][b][sq * PH + row * 32];                \
            _Pragma("unroll")                                                 \
            for (int part = 0; part < 4; ++part) {                            \
                f16x8 w;                                                      \
                _Pragma("unroll")                                             \
                for (int e = 0; e < 8; ++e) {                                 \
                    const int k = part * 8 + e;                               \
                    w[e] = (k < D) ? (_Float16)rp[k]                          \
                         : (k == D) ? (_Float16)1.0f : (_Float16)0.0f;        \
                }                                                             \
                *reinterpret_cast<f16x8*>(wp + part * 8) = w;                 \
            }                                                                 \
        }                                                                     \
    }

    // ---- prologue: stage + convert chunk 0 ----
    STAGE_RAW(0);
    asm volatile("s_waitcnt vmcnt(0)" ::: "memory");
    CONVERT(0);

    #pragma unroll 1
    for (int c = 0; c < NCHK; ++c) {
        // 1) fire next chunk's staging; pin it before the serial region
        if (c + 1 < NCHK) STAGE_RAW(c + 1);
        asm volatile("" ::: "memory");

        const _Float16* rdp = &xf16[dirw][c & 1][sd * PH + ug * 8];

        // 2) serial 8 steps, rolling 1-ahead frag prefetch (2 frags live)
        f16x8 hrow[4];
        f16x8 fA = *reinterpret_cast<const f16x8*>(rdp);
        #pragma unroll
        for (int ls = 0; ls < CHUNK; ++ls) {
            f16x8 fB;
            if (ls + 1 < CHUNK)
                fB = *reinterpret_cast<const f16x8*>(rdp + (ls + 1) * 32);

            const f32x4 gxr = __builtin_amdgcn_mfma_f32_16x16x32_f16(wihA[0], fA, z4, 0, 0, 0);
            const f32x4 gxz = __builtin_amdgcn_mfma_f32_16x16x32_f16(wihA[1], fA, z4, 0, 0, 0);
            const f32x4 gxn = __builtin_amdgcn_mfma_f32_16x16x32_f16(wihA[2], fA, z4, 0, 0, 0);
            const f32x4 ghr = __builtin_amdgcn_mfma_f32_16x16x16f16(whhA[0], bcur, z4, 0, 0, 0);
            const f32x4 ghz = __builtin_amdgcn_mfma_f32_16x16x16f16(whhA[1], bcur, z4, 0, 0, 0);
            const f32x4 ghn = __builtin_amdgcn_mfma_f32_16x16x16f16(whhA[2], bcur, z4, 0, 0, 0);

            #pragma unroll
            for (int e = 0; e < 4; ++e) {
                const float rr = RCPF(1.0f + EXP2F(-(gxr[e] + ghr[e])));
                const float zz = RCPF(1.0f + EXP2F(-(gxz[e] + ghz[e])));
                const float nv = tanh_pre(gxn[e] + rr * (ghn[e] + bhn[e]));
                hw[e] = nv + zz * (hw[e] - nv);
                const _Float16 hh16 = (_Float16)hw[e];
                bcur[e] = hh16;
                hrow[e][ls] = hh16;
            }
            if (ls + 1 < CHUNK) fA = fB;
        }

        // 3) history store: 4x 16B contiguous per lane; bwd chunk-reversed
        const int cc2 = dir ? (NCHK - 1 - c) : c;
        _Float16* gp2 = ghbase + (size_t)cc2 * 256;
        #pragma unroll
        for (int e = 0; e < 4; ++e)
            *reinterpret_cast<f16x8*>(gp2 + e * 8) = hrow[e];

        // 4) drain staging loads ONLY (stores stay in flight), convert next
        if (c + 1 < NCHK) {
            asm volatile("s_waitcnt vmcnt(4)" ::: "memory");
            CONVERT((c + 1) & 1);
        }
    }
    #undef STAGE_RAW
    #undef STAGE_ONE
    #undef CONVERT
}

// ---------------- K1b: scalar-load variant (stage 2: L2-resident input) ----
// Verbatim R19 structure: register-resident rows, compiler-precise waits.
template<int D>
__global__ __launch_bounds__(128, 1)
void gru_serial_scalar(
    const float* __restrict__ x,                      // [S, TSTEPS, D]
    const float* __restrict__ Wih_f, const float* __restrict__ Whh_f,
    const float* __restrict__ bih_f, const float* __restrict__ bhh_f,
    const float* __restrict__ Wih_b, const float* __restrict__ Whh_b,
    const float* __restrict__ bih_b, const float* __restrict__ bhh_b,
    _Float16* __restrict__ ghist)
{
    __shared__ __align__(16) _Float16 xstage[2 * 2 * 16 * PH];

    const int tid  = threadIdx.x;
    const int lane = tid & 63;
    const int dir  = tid >> 6;
    const int sd   = lane & 15;
    const int ug   = lane >> 4;

    const float* WihP = dir ? Wih_b : Wih_f;
    const float* WhhP = dir ? Whh_b : Whh_f;
    const float* bihP = dir ? bih_b : bih_f;
    const float* bhhP = dir ? bhh_b : bhh_f;

    h4 whhA[3];
    #pragma unroll
    for (int n = 0; n < 3; ++n) {
        const float sc = (n < 2) ? SC1 : SC2;
        const int g = 16 * n + sd;
        #pragma unroll
        for (int e = 0; e < 4; ++e)
            whhA[n][e] = (_Float16)(WhhP[g * HD + 4 * ug + e] * sc);
    }
    f16x8 wihA[3];
    #pragma unroll
    for (int n = 0; n < 3; ++n) {
        const float sc = (n < 2) ? SC1 : SC2;
        const int g = 16 * n + sd;
        const float bias = (n < 2) ? (bihP[g] + bhhP[g]) : bihP[g];
        #pragma unroll
        for (int e = 0; e < 8; ++e) {
            const int k = 8 * ug + e;
            wihA[n][e] = (k < D) ? (_Float16)(WihP[g * D + k] * sc)
                       : (k == D) ? (_Float16)(bias * sc)
                       : (_Float16)0.0f;
        }
    }
    float bhn[4];
    #pragma unroll
    for (int e = 0; e < 4; ++e)
        bhn[e] = bhhP[2 * HD + 4 * ug + e] * SC2;

    const int sst = lane >> 2;
    const int pst = lane & 3;
    const int ls0 = 2 * pst, ls1 = ls0 + 1;
    const float* xseq = x + (size_t)(blockIdx.x * 16 + sst) * (TSTEPS * D);

    _Float16* mybuf = xstage + dir * (2 * 16 * PH);
    _Float16* wpr0  = mybuf + sst * PH + ls0 * 32;
    _Float16* wpr1  = mybuf + sst * PH + ls1 * 32;

    {
        const int t0 = dir ? (TSTEPS - 1 - ls0) : ls0;
        const int t1 = dir ? (TSTEPS - 1 - ls1) : ls1;
        const float* r0 = xseq + (size_t)t0 * D;
        const float* r1 = xseq + (size_t)t1 * D;
        float rA[D], rB[D];
        #pragma unroll
        for (int k = 0; k < D; ++k) { rA[k] = r0[k]; rB[k] = r1[k]; }
        store_row<D>(wpr0, rA);
        store_row<D>(wpr1, rB);
    }

    h4 bcur = (h4){(_Float16)0.0f, (_Float16)0.0f, (_Float16)0.0f, (_Float16)0.0f};
    float hw[4] = {0.0f, 0.0f, 0.0f, 0.0f};
    _Float16* ghbase = ghist + (size_t)(blockIdx.x * 16 + sd) * SEQ_HALFS
                       + (size_t)(dir * 16 + 4 * ug) * 8;
    const f32x4 z4 = {0.f, 0.f, 0.f, 0.f};

    #pragma unroll 1
    for (int c = 0; c < NCHK; ++c) {
        float rA[D], rB[D];
        if (c + 1 < NCHK) {
            const int s0 = (c + 1) * CHUNK + ls0;
            const int s1 = (c + 1) * CHUNK + ls1;
            const int t0 = dir ? (TSTEPS - 1 - s0) : s0;
            const int t1 = dir ? (TSTEPS - 1 - s1) : s1;
            const float* r0 = xseq + (size_t)t0 * D;
            const float* r1 = xseq + (size_t)t1 * D;
            #pragma unroll
            for (int k = 0; k < D; ++k) { rA[k] = r0[k]; rB[k] = r1[k]; }
        }

        const _Float16* rdp = mybuf + (c & 1) * (16 * PH) + sd * PH + ug * 8;
        f16x8 hrow[4];
        #pragma unroll
        for (int ls = 0; ls < CHUNK; ++ls) {
            const f16x8 frag = *reinterpret_cast<const f16x8*>(rdp + ls * 32);

            const f32x4 gxr = __builtin_amdgcn_mfma_f32_16x16x32_f16(wihA[0], frag, z4, 0, 0, 0);
            const f32x4 gxz = __builtin_amdgcn_mfma_f32_16x16x32_f16(wihA[1], frag, z4, 0, 0, 0);
            const f32x4 gxn = __builtin_amdgcn_mfma_f32_16x16x32_f16(wihA[2], frag, z4, 0, 0, 0);
            const f32x4 ghr = __builtin_amdgcn_mfma_f32_16x16x16f16(whhA[0], bcur, z4, 0, 0, 0);
            const f32x4 ghz = __builtin_amdgcn_mfma_f32_16x16x16f16(whhA[1], bcur, z4, 0, 0, 0);
            const f32x4 ghn = __builtin_amdgcn_mfma_f32_16x16x16f16(whhA[2], bcur, z4, 0, 0, 0);

            #pragma unroll
            for (int e = 0; e < 4; ++e) {
                const float rr = RCPF(1.0f + EXP2F(-(gxr[e] + ghr[e])));
                const float zz = RCPF(1.0f + EXP2F(-(gxz[e] + ghz[e])));
                const float nv = tanh_pre(gxn[e] + rr * (ghn[e] + bhn[e]));
                hw[e] = nv + zz * (hw[e] - nv);
                const _Float16 hh16 = (_Float16)hw[e];
                bcur[e] = hh16;
                hrow[e][ls] = hh16;
            }
        }

        const int cc = dir ? (NCHK - 1 - c) : c;
        _Float16* gp = ghbase + (size_t)cc * 256;
        #pragma unroll
        for (int e = 0; e < 4; ++e)
            *reinterpret_cast<f16x8*>(gp + e * 8) = hrow[e];

        if (c + 1 < NCHK) {
            const int bs = ((c + 1) & 1) * (16 * PH);
            store_row<D>(wpr0 + bs, rA);
            store_row<D>(wpr1 + bs, rB);
        }
    }
}

// ---------------- K2: attention over the streamed history (unchanged) ------
template<bool HAS_PROJ>
__global__ __launch_bounds__(128, 4)
void attn_kernel(
    const _Float16* __restrict__ ghist,
    const float* __restrict__ Wa, const float* __restrict__ ba,
    const float* __restrict__ ctxv,
    const float* __restrict__ Wm, const float* __restrict__ bm,
    float* __restrict__ out, int out_cols)
{
    __shared__ __align__(16) _Float16 h1[TSTEPS * H1W];   // 9216 B
    __shared__ float w_sh[TSTEPS];
    __shared__ float red[4];
    __shared__ float cvp[4 * AD];

    const int tid  = threadIdx.x;
    const int lane = tid & 63;
    const int wave = tid >> 6;
    const int seq  = blockIdx.x;

    {
        const f16x8* src = reinterpret_cast<const f16x8*>(ghist + (size_t)seq * SEQ_HALFS);
        #pragma unroll
        for (int k = 0; k < 4; ++k) {
            const int idx = tid + k * 128;
            const f16x8 v = src[idx];
            const int u32 = idx & 31;
            const int tb  = (idx >> 5) * 8;
            const int flip = (u32 >= 16) ? 7 : 0;   // bwd chunks are s-ordered
            #pragma unroll
            for (int e = 0; e < 8; ++e)
                h1[(tb + (e ^ flip)) * H1W + u32] = v[e];
        }
    }
    __syncthreads();

    {
        const int t = tid;
        float hh[AD];
        const h4* hr = reinterpret_cast<const h4*>(&h1[t * H1W]);
        #pragma unroll
        for (int pp = 0; pp < AD / 4; ++pp) {
            const h4 v = hr[pp];
            #pragma unroll
            for (int e = 0; e < 4; ++e) hh[4 * pp + e] = (float)v[e];
        }
        float st = 0.0f;
        for (int i = 0; i < AD; ++i) {
            float a0 = ba[i], a1 = 0.f;
            const float* war = &Wa[i * AD];
            #pragma unroll
            for (int k = 0; k < AD; k += 2) {
                a0 += war[k] * hh[k];
                a1 += war[k + 1] * hh[k + 1];
            }
            st += tanh_pre(SC2 * (a0 + a1)) * ctxv[i];
        }
        float m = st;
        #pragma unroll
        for (int off = 32; off > 0; off >>= 1) m = fmaxf(m, __shfl_xor(m, off));
        if (lane == 0) red[wave] = m;
        __syncthreads();
        m = fmaxf(red[0], red[1]);
        const float e = EXP2F(SC1 * (st - m));
        float ssum = e;
        #pragma unroll
        for (int off = 32; off > 0; off >>= 1) ssum += __shfl_xor(ssum, off);
        if (lane == 0) red[2 + wave] = ssum;
        __syncthreads();
        const float Z = red[2] + red[3];
        w_sh[tid] = e * RCPF(Z);
    }
    __syncthreads();

    {
        const int g = tid >> 5, i = tid & 31;
        float acc = 0.0f;
        for (int k = 0; k < 32; ++k) {
            const int tt = g * 32 + k;
            acc += w_sh[tt] * (float)h1[tt * H1W + i];
        }
        cvp[g * AD + i] = acc;
    }
    __syncthreads();
    if (tid < AD)
        cvp[tid] = cvp[tid] + cvp[AD + tid] + cvp[2 * AD + tid] + cvp[3 * AD + tid];
    __syncthreads();

    if (HAS_PROJ) {
        if (tid < HD) {
            float acc = bm[tid];
            #pragma unroll
            for (int i = 0; i < AD; ++i) acc += Wm[tid * AD + i] * cvp[i];
            out[(size_t)seq * out_cols + tid] = acc;
        }
    } else {
        if (tid < AD) out[(size_t)seq * out_cols + tid] = cvp[tid];
    }
}

extern "C" void kernel_launch(void* const* d_in, const int* in_sizes, int n_in,
                              void* d_out, int out_size, void* d_ws, size_t ws_size,
                              hipStream_t stream) {
    const float* x     = (const float*)d_in[0];
    const float* Wih1f = (const float*)d_in[1];
    const float* Whh1f = (const float*)d_in[2];
    const float* bih1f = (const float*)d_in[3];
    const float* bhh1f = (const float*)d_in[4];
    const float* Wih1b = (const float*)d_in[5];
    const float* Whh1b = (const float*)d_in[6];
    const float* bih1b = (const float*)d_in[7];
    const float* bhh1b = (const float*)d_in[8];
    const float* Wih2f = (const float*)d_in[9];
    const float* Whh2f = (const float*)d_in[10];
    const float* bih2f = (const float*)d_in[11];
    const float* bhh2f = (const float*)d_in[12];
    const float* Wih2b = (const float*)d_in[13];
    const float* Whh2b = (const float*)d_in[14];
    const float* bih2b = (const float*)d_in[15];
    const float* bhh2b = (const float*)d_in[16];
    const float* Wa1   = (const float*)d_in[17];
    const float* ba1   = (const float*)d_in[18];
    const float* ctx1  = (const float*)d_in[19];
    const float* Wa2   = (const float*)d_in[20];
    const float* ba2   = (const float*)d_in[21];
    const float* ctx2  = (const float*)d_in[22];
    const float* Wm    = (const float*)d_in[23];
    const float* bm    = (const float*)d_in[24];

    float* flow = (float*)d_ws;                               // [8192,16] = 512KB
    const size_t histOff = 1u << 20;                          // 1 MB
    _Float16* ghist = (_Float16*)((char*)d_ws + histOff);     // 64 MB (reused by s2)
    float* outp = (float*)d_out;                              // [64, 32]

    // Stage 1: 8192 seqs, 16 per block (HBM input -> glds staging)
    gru_serial_glds<25><<<512, 128, 0, stream>>>(
        x, Wih1f, Whh1f, bih1f, bhh1f, Wih1b, Whh1b, bih1b, bhh1b, ghist);
    attn_kernel<true><<<8192, 128, 0, stream>>>(
        ghist, Wa1, ba1, ctx1, Wm, bm, flow, 16);

    // Stage 2: 64 seqs (L2-resident input -> scalar staging)
    gru_serial_scalar<16><<<4, 128, 0, stream>>>(
        flow, Wih2f, Whh2f, bih2f, bhh2f, Wih2b, Whh2b, bih2b, bhh2b, ghist);
    attn_kernel<false><<<64, 128, 0, stream>>>(
        ghist, Wa2, ba2, ctx2, nullptr, nullptr, outp, 32);
}